// Round 16
// baseline (82.005 us; speedup 1.0000x reference)
//
#include <hip/hip_runtime.h>
#include <cstddef>

#define B_  2
#define N_  2048
#define L_  5
#define HH  8
#define P_  4
#define S_  21824
#define DQK 32

using bf16x8 = __attribute__((ext_vector_type(8))) short;
using f32x4  = __attribute__((ext_vector_type(4))) float;
using us8    = __attribute__((ext_vector_type(8))) unsigned short;
using h2     = __attribute__((ext_vector_type(2))) _Float16;

__device__ __forceinline__ unsigned short f2b(float f) {
  unsigned u = __builtin_bit_cast(unsigned, f);
  u += 0x7FFFu + ((u >> 16) & 1u);            // round-to-nearest-even
  return (unsigned short)(u >> 16);
}
__device__ __forceinline__ float b2f(unsigned short h) {
  return __builtin_bit_cast(float, ((unsigned)h) << 16);
}
// packed f32x2 -> bf16x2 (RNE): lo -> low16, hi -> high16
__device__ __forceinline__ unsigned cvtpk(float lo, float hi) {
  unsigned r;
  asm("v_cvt_pk_bf16_f32 %0, %1, %2" : "=v"(r) : "v"(lo), "v"(hi));
  return r;
}
// packed f32x2 -> f16x2 (RTZ) with explicit bit_casts (builtin returns __fp16x2)
__device__ __forceinline__ h2 pkrtz(float a, float b) {
  return __builtin_bit_cast(h2, __builtin_amdgcn_cvt_pkrtz(a, b));
}
__device__ __forceinline__ unsigned pkrtz_u(float a, float b) {
  return __builtin_bit_cast(unsigned, __builtin_amdgcn_cvt_pkrtz(a, b));
}
__device__ __forceinline__ h2 u2h(unsigned u) { return __builtin_bit_cast(h2, u); }

__device__ __forceinline__ void gld_lds16(const void* g, void* l) {
  __builtin_amdgcn_global_load_lds(
      (const __attribute__((address_space(1))) unsigned int*)g,
      (__attribute__((address_space(3))) unsigned int*)l, 16, 0, 0);
}

// DPP-based add: v += permuted(v). VALU pipe, no LDS round-trip.
template <int CTRL>
__device__ __forceinline__ float dppadd(float v) {
  const int x = __builtin_bit_cast(int, v);
  return v + __builtin_bit_cast(float,
      __builtin_amdgcn_update_dpp(x, x, CTRL, 0xF, 0xF, false));
}

// ---------------------------------------------------------------------------
// cvt_all: small tensors only (sfeats is consumed as f32 by the kv GEMM).
// ---------------------------------------------------------------------------
#define F0 131072   // in_feats -> if_hi + if_lo   (4096*256/8)
#define F1 147456   // + W_kv -> wkv_bf            (512*256/8)
#define F2 155648   // + W_q  -> wq_bf             (256*256/8)
#define F3 163840   // + W_out -> wout_bf          (256*256/8)
#define F4 176128   // + W_off(pad384) -> woff_hi  (384*256/8)
#define F5 188416   // + W_off(pad384) -> woff_lo  (384*256/8)

__device__ __forceinline__ void cvt8_plain(const float* s, unsigned short* d, int u) {
  const float4 a = ((const float4*)s)[2 * u];
  const float4 b = ((const float4*)s)[2 * u + 1];
  us8 o;
  o[0] = f2b(a.x); o[1] = f2b(a.y); o[2] = f2b(a.z); o[3] = f2b(a.w);
  o[4] = f2b(b.x); o[5] = f2b(b.y); o[6] = f2b(b.z); o[7] = f2b(b.w);
  ((us8*)d)[u] = o;
}
__device__ __forceinline__ unsigned short f2b_lo(float x) {
  return f2b(x - b2f(f2b(x)));
}
__device__ __forceinline__ void cvt8_lo(const float* s, unsigned short* d, int u) {
  const float4 a = ((const float4*)s)[2 * u];
  const float4 b = ((const float4*)s)[2 * u + 1];
  us8 o;
  o[0] = f2b_lo(a.x); o[1] = f2b_lo(a.y); o[2] = f2b_lo(a.z); o[3] = f2b_lo(a.w);
  o[4] = f2b_lo(b.x); o[5] = f2b_lo(b.y); o[6] = f2b_lo(b.z); o[7] = f2b_lo(b.w);
  ((us8*)d)[u] = o;
}
__device__ __forceinline__ void cvt8_both(const float* s, unsigned short* dh,
                                          unsigned short* dl, int u) {
  const float4 a = ((const float4*)s)[2 * u];
  const float4 b = ((const float4*)s)[2 * u + 1];
  us8 oh, ol;
  const float v[8] = {a.x, a.y, a.z, a.w, b.x, b.y, b.z, b.w};
#pragma unroll
  for (int k = 0; k < 8; ++k) {
    const unsigned short hh = f2b(v[k]);
    oh[k] = hh;
    ol[k] = f2b(v[k] - b2f(hh));
  }
  ((us8*)dh)[u] = oh;
  ((us8*)dl)[u] = ol;
}

__global__ __launch_bounds__(256) void cvt_all(
    const float* __restrict__ in_feats, const float* __restrict__ W_kv,
    const float* __restrict__ W_q, const float* __restrict__ W_out,
    const float* __restrict__ W_off,
    unsigned short* __restrict__ if_hi, unsigned short* __restrict__ if_lo,
    unsigned short* __restrict__ wkv_bf, unsigned short* __restrict__ wq_bf,
    unsigned short* __restrict__ wout_bf, unsigned short* __restrict__ woff_hi,
    unsigned short* __restrict__ woff_lo) {
  const int i = blockIdx.x * 256 + threadIdx.x;
  if      (i < F0) cvt8_both(in_feats, if_hi, if_lo, i);
  else if (i < F1) cvt8_plain(W_kv, wkv_bf, i - F0);
  else if (i < F2) cvt8_plain(W_q, wq_bf, i - F1);
  else if (i < F3) cvt8_plain(W_out, wout_bf, i - F2);
  else if (i < F4) {
    const int u = i - F3;
    if ((u >> 5) < 320) cvt8_plain(W_off, woff_hi, u);
    else ((us8*)woff_hi)[u] = (us8)0;
  } else {
    const int u = i - F4;
    if ((u >> 5) < 320) cvt8_lo(W_off, woff_lo, u);
    else ((us8*)woff_lo)[u] = (us8)0;
  }
}

// ---------------------------------------------------------------------------
// Classic staged MFMA tile (128x128, BK=64) for off/q/out (proven body).
// ---------------------------------------------------------------------------
__device__ __forceinline__ void mfma_compute(
    const unsigned short* As, const unsigned short* Bs,
    int wr, int wc, int fr, int fq, f32x4 (&acc)[4][4]) {
#pragma unroll
  for (int kk = 0; kk < 2; ++kk) {
    bf16x8 af[4], bfv[4];
#pragma unroll
    for (int i = 0; i < 4; ++i) {
      const int ar = wr * 64 + i * 16 + fr;
      const int cha = (kk * 4 + fq) ^ (ar & 7);
      af[i] = *(const bf16x8*)(As + ar * 64 + cha * 8);
      const int br = wc * 64 + i * 16 + fr;
      const int chb = (kk * 4 + fq) ^ (br & 7);
      bfv[i] = *(const bf16x8*)(Bs + br * 64 + chb * 8);
    }
#pragma unroll
    for (int i = 0; i < 4; ++i)
#pragma unroll
      for (int j = 0; j < 4; ++j)
        acc[i][j] = __builtin_amdgcn_mfma_f32_16x16x32_bf16(
            af[i], bfv[j], acc[i][j], 0, 0, 0);
  }
}

__device__ __forceinline__ void mfma_tile_bf16(
    const unsigned short* __restrict__ Ap, const unsigned short* __restrict__ Wp,
    unsigned short* As, unsigned short* Bs,
    int row0, int col0, int wv, int wr, int wc, int fr, int fq,
    int srow, int sch, f32x4 (&acc)[4][4]) {
  for (int k0 = 0; k0 < 256; k0 += 64) {
#pragma unroll
    for (int i = 0; i < 4; ++i) {
      const int r = i * 32 + srow;
      const int ca = sch ^ (r & 7);
      gld_lds16(Ap + (size_t)(row0 + r) * 256 + k0 + ca * 8,
                As + (size_t)(i * 32 + wv * 8) * 64);
      gld_lds16(Wp + (size_t)(col0 + r) * 256 + k0 + ca * 8,
                Bs + (size_t)(i * 32 + wv * 8) * 64);
    }
    __syncthreads();
    mfma_compute(As, Bs, wr, wc, fr, fq, acc);
    __syncthreads();
  }
}

// ---------------------------------------------------------------------------
// Ubergemm: off [0,96) | q [96,160) | kv [160,1536).
// kv path: A staged RAW F32 via global_load_lds (inverse-swizzled source),
// BK=32 dbuf, counted vmcnt(6); f32->bf16 cvt in regs between ds_read and
// MFMA. B bf16 with 2-ROW-WINDOW swizzle (cc^((rw>>1)&3)) -> 2-way banks
// (free) instead of 4-way. setprio(1) around MFMA cluster (T5).
// ---------------------------------------------------------------------------
__global__ __launch_bounds__(256) void ubergemm(
    const float* __restrict__ sfeats,
    const unsigned short* __restrict__ wkv_bf,
    const unsigned short* __restrict__ if_hi,
    const unsigned short* __restrict__ if_lo,
    const unsigned short* __restrict__ woff_hi,
    const unsigned short* __restrict__ woff_lo,
    const unsigned short* __restrict__ wq_bf,
    const float* __restrict__ b_kv, const float* __restrict__ b_off,
    const float* __restrict__ b_q,
    unsigned short* __restrict__ kvt, float* __restrict__ offb,
    float* __restrict__ qb) {
  __shared__ __align__(16) unsigned char ldsraw[49152];   // 48 KB

  const int tid = threadIdx.x;
  const int lane = tid & 63;
  const int wv = tid >> 6;
  const int wr = wv >> 1, wc = wv & 1;
  const int fr = lane & 15, fq = lane >> 4;
  const int bx = blockIdx.x;

  f32x4 acc[4][4] = {};

  if (bx >= 160) {          // ---- kv path ----
    const int t = bx - 160;
    const int x = t & 7;
    const int idx = t >> 3;
    const int c = idx & 3;
    const int g = (idx >> 2) * 8 + x;
    if (g >= 341) return;
    const int row0 = g * 128;
    const int col0 = c * 128;

    // A buffers: f32 [128][32] = 16 KB each; B buffers: bf16 [128][32] = 8 KB
    float* Afb[2] = {(float*)ldsraw, (float*)(ldsraw + 16384)};
    unsigned short* Bb[2] = {(unsigned short*)(ldsraw + 32768),
                             (unsigned short*)(ldsraw + 40960)};

    // stage: 4 A-chunks (f32) + 2 B-chunks (bf16) per thread = 6 vmem ops
#define KV_STAGE(KK, BUF)                                                     \
    {                                                                         \
      _Pragma("unroll")                                                       \
      for (int ld = 0; ld < 4; ++ld) {   /* A: 1024 chunks of 16B */          \
        const int ci = ld * 256 + tid;                                        \
        const int rw = ci >> 3, cc = ci & 7;                                  \
        const int ca = cc ^ (rw & 7);                                         \
        gld_lds16(sfeats + (size_t)(row0 + rw) * 256 + (KK) * 32 + ca * 4,    \
                  (char*)Afb[BUF] + (ld * 4096 + wv * 1024));                 \
      }                                                                       \
      _Pragma("unroll")                                                       \
      for (int ld = 0; ld < 2; ++ld) {   /* B: 512 chunks of 16B */           \
        const int ci = ld * 256 + tid;                                        \
        const int rw = ci >> 2, cc = ci & 3;                                  \
        const int ca = cc ^ ((rw >> 1) & 3);   /* 2-row-window swizzle */     \
        gld_lds16(wkv_bf + (size_t)(col0 + rw) * 256 + (KK) * 32 + ca * 8,    \
                  (char*)Bb[BUF] + (ld * 4096 + wv * 1024));                  \
      }                                                                       \
    }

    KV_STAGE(0, 0);
#pragma unroll
    for (int k = 0; k < 8; ++k) {
      if (k < 7) {
        KV_STAGE(k + 1, (k + 1) & 1);
        asm volatile("s_waitcnt vmcnt(6)" ::: "memory");
      } else {
        asm volatile("s_waitcnt vmcnt(0)" ::: "memory");
      }
      __builtin_amdgcn_s_barrier();
      __builtin_amdgcn_sched_barrier(0);
      const float* Ac = Afb[k & 1];
      const unsigned short* Bc = Bb[k & 1];
      bf16x8 af[4], bfv[4];
#pragma unroll
      for (int i = 0; i < 4; ++i) {
        const int ar = wr * 64 + i * 16 + fr;
        const int swz = ar & 7;
        const float4 a0 = *(const float4*)(Ac + ar * 32 + (((fq * 2) ^ swz) * 4));
        const float4 a1 = *(const float4*)(Ac + ar * 32 + (((fq * 2 + 1) ^ swz) * 4));
        uint4 u;
        u.x = cvtpk(a0.x, a0.y);
        u.y = cvtpk(a0.z, a0.w);
        u.z = cvtpk(a1.x, a1.y);
        u.w = cvtpk(a1.z, a1.w);
        af[i] = __builtin_bit_cast(bf16x8, u);
      }
#pragma unroll
      for (int j = 0; j < 4; ++j) {
        const int nr = wc * 64 + j * 16 + fr;
        bfv[j] = *(const bf16x8*)(Bc + (nr * 4 + (fq ^ ((nr >> 1) & 3))) * 8);
      }
      __builtin_amdgcn_s_setprio(1);
#pragma unroll
      for (int j = 0; j < 4; ++j)
#pragma unroll
        for (int i = 0; i < 4; ++i)
          acc[j][i] = __builtin_amdgcn_mfma_f32_16x16x32_bf16(
              bfv[j], af[i], acc[j][i], 0, 0, 0);   // swapped: C^T fragments
      __builtin_amdgcn_s_setprio(0);
      __builtin_amdgcn_s_barrier();
    }
#undef KV_STAGE

    // epilogue: lane holds 4 consecutive channels per tile -> f16 dword stores
#pragma unroll
    for (int j = 0; j < 4; ++j) {
      const int c0 = col0 + wc * 64 + j * 16 + fq * 4;
      const float4 bb = *(const float4*)(b_kv + c0);
      const int h = c0 >> 6;
      const int cc = c0 & 63;
#pragma unroll
      for (int i = 0; i < 4; ++i) {
        const int sl = row0 + wr * 64 + i * 16 + fr;
        const int b = (sl >= S_) ? 1 : 0;
        const int s = sl - b * S_;
        unsigned* dst = (unsigned*)(kvt + ((size_t)(b * HH + h) * S_ + s) * 64 + cc);
        dst[0] = pkrtz_u(acc[j][i][0] + bb.x, acc[j][i][1] + bb.y);
        dst[1] = pkrtz_u(acc[j][i][2] + bb.z, acc[j][i][3] + bb.w);
      }
    }
    return;
  }

  // ---- off / q paths (classic staged tiles, first 32 KB of LDS) ----
  unsigned short* As = (unsigned short*)ldsraw;
  unsigned short* Bs = (unsigned short*)(ldsraw + 16384);
  const int srow = tid >> 3;
  const int sch = tid & 7;
  int row0, col0, ldc, nbias;
  const float* bias;
  float* Cf;
  if (bx < 96) {            // off: 3 K-segments, bf16x3
    col0 = (bx % 3) * 128; row0 = (bx / 3) * 128;
    bias = b_off; Cf = offb; ldc = 384; nbias = 320;
    mfma_tile_bf16(if_hi, woff_hi, As, Bs, row0, col0, wv, wr, wc, fr, fq, srow, sch, acc);
    mfma_tile_bf16(if_hi, woff_lo, As, Bs, row0, col0, wv, wr, wc, fr, fq, srow, sch, acc);
    mfma_tile_bf16(if_lo, woff_hi, As, Bs, row0, col0, wv, wr, wc, fr, fq, srow, sch, acc);
  } else {                  // q
    const int t = bx - 96;
    col0 = (t & 1) * 128; row0 = (t >> 1) * 128;
    bias = b_q; Cf = qb; ldc = 256; nbias = 256;
    mfma_tile_bf16(if_hi, wq_bf, As, Bs, row0, col0, wv, wr, wc, fr, fq, srow, sch, acc);
  }

#pragma unroll
  for (int j = 0; j < 4; ++j) {
    const int n = col0 + wc * 64 + j * 16 + fr;
    const float bv = (n < nbias) ? bias[n] : 0.f;
#pragma unroll
    for (int i = 0; i < 4; ++i) {
      const int mbase = row0 + wr * 64 + i * 16 + fq * 4;
#pragma unroll
      for (int r = 0; r < 4; ++r)
        Cf[(size_t)(mbase + r) * ldc + n] = acc[i][j][r] + bv;
    }
  }
}

// ---------------------------------------------------------------------------
// out-projection GEMM: bf16 MFMA, f32 out.
// ---------------------------------------------------------------------------
__global__ __launch_bounds__(256) void gemm_out(
    const unsigned short* __restrict__ A, const unsigned short* __restrict__ Wt,
    const float* __restrict__ bias, float* __restrict__ C) {
  __shared__ __align__(16) unsigned short As[128 * 64];
  __shared__ __align__(16) unsigned short Bs[128 * 64];
  const int tid = threadIdx.x;
  const int lane = tid & 63;
  const int wv = tid >> 6;
  const int wr = wv >> 1, wc = wv & 1;
  const int fr = lane & 15, fq = lane >> 4;
  const int row0 = blockIdx.y * 128, col0 = blockIdx.x * 128;
  const int srow = tid >> 3, sch = tid & 7;
  f32x4 acc[4][4] = {};
  mfma_tile_bf16(A, Wt, As, Bs, row0, col0, wv, wr, wc, fr, fq, srow, sch, acc);
#pragma unroll
  for (int j = 0; j < 4; ++j) {
    const int n = col0 + wc * 64 + j * 16 + fr;
    const float bv = bias[n];
#pragma unroll
    for (int i = 0; i < 4; ++i) {
      const int mbase = row0 + wr * 64 + i * 16 + fq * 4;
#pragma unroll
      for (int r = 0; r < 4; ++r)
        C[(size_t)(mbase + r) * 256 + n] = acc[i][j][r] + bv;
    }
  }
}

// ---------------------------------------------------------------------------
// sample_attn6: packed-f16 math. kvt is f16; bilinear = v_pk_fma_f16;
// logit = v_dot2_f32_f16. Slice-phased XCD decode + 5-deep gather prefetch.
// ---------------------------------------------------------------------------
__global__ __launch_bounds__(256) void sample_attn6(
    const unsigned short* __restrict__ kvt, // [B*HH, S, 64] f16
    const float* __restrict__ offb,         // [B*N, 384]
    const float* __restrict__ qb,           // [B*N, 256]
    const float* __restrict__ priors,       // [B, N, L, 2]
    const int* __restrict__ shapes,         // [L, 2] (H, W)
    const int* __restrict__ starts,         // [L]
    const float* __restrict__ pencs,        // [HH, 20, 32]
    unsigned short* __restrict__ wtd) {     // [B*N, 256] bf16
  __shared__ __align__(16) int pbuf[4][20][8];
  const int wv = threadIdx.x >> 6;
  const int lane = threadIdx.x & 63;
  const int beta = blockIdx.x;
  const int sig = (beta & 7) * 2 + (beta >> 12);        // slice 0..15
  const int chunk = (beta >> 3) & 511;                  // 0..511
  const int h = sig & 7;
  const int b = sig >> 3;
  const int bn = b * N_ + chunk * 4 + wv;
  const int j = lane & 31;
  const int half = lane >> 5;

  if (lane < 20) {
    const int pp = lane;
    const int l = pp >> 2;
    const float2 oxy = *(const float2*)(offb + (size_t)bn * 384 + h * 40 + pp * 2);
    const float2 pxy = *(const float2*)(priors + ((size_t)bn * 5 + l) * 2);
    const int Wd = shapes[l * 2 + 1];
    const int Hd = shapes[l * 2 + 0];
    const int st = starts[l];
    const float Wf = (float)Wd, Hf = (float)Hd;
    const float x = (pxy.x + oxy.x / Wf) * Wf - 0.5f;
    const float y = (pxy.y + oxy.y / Hf) * Hf - 0.5f;
    const float x0f = floorf(x), y0f = floorf(y);
    const float fx = x - x0f, fy = y - y0f;
    const int xi = (int)x0f, yi = (int)y0f;
    int a[4]; unsigned wpk[4];
#pragma unroll
    for (int dy = 0; dy < 2; ++dy)
#pragma unroll
      for (int dx = 0; dx < 2; ++dx) {
        const int xc = xi + dx, yc = yi + dy;
        const bool valid = (xc >= 0) & (xc < Wd) & (yc >= 0) & (yc < Hd);
        const float wt = (dx ? fx : 1.f - fx) * (dy ? fy : 1.f - fy);
        const float wm = valid ? wt : 0.f;
        const int xcc = min(max(xc, 0), Wd - 1);
        const int ycc = min(max(yc, 0), Hd - 1);
        a[dy * 2 + dx] = (st + ycc * Wd + xcc) * 32;
        wpk[dy * 2 + dx] = pkrtz_u(wm, wm);  // duplicated half2
      }
    *(int4*)&pbuf[wv][pp][0] = make_int4(a[0], a[1], a[2], a[3]);
    *(int4*)&pbuf[wv][pp][4] =
        make_int4((int)wpk[0], (int)wpk[1], (int)wpk[2], (int)wpk[3]);
  }

  const int jc = j & 15;
  float2 q2 = *(const float2*)(qb + (size_t)bn * 256 + h * DQK + 2 * jc);
  q2.x *= 0.17677669529663687f;
  q2.y *= 0.17677669529663687f;
  const h2 qpk = pkrtz(q2.x, q2.y);
  float qpe[10];
#pragma unroll
  for (int i = 0; i < 10; ++i) {
    const float2 pe = *(const float2*)(
        pencs + ((size_t)h * 20 + 2 * i + half) * DQK + 2 * jc);
    qpe[i] = q2.x * pe.x + q2.y * pe.y;
  }

  const unsigned* kvd = (const unsigned*)(kvt + (size_t)(b * HH + h) * (S_ * 64));

  uint4 wwp[5];
  unsigned g[5][4];
#pragma unroll
  for (int i = 0; i < 5; ++i) {
    const int4 aa = *(const int4*)&pbuf[wv][2 * i + half][0];
    wwp[i] = *(const uint4*)&pbuf[wv][2 * i + half][4];
    g[i][0] = kvd[(unsigned)aa.x + j];
    g[i][1] = kvd[(unsigned)aa.y + j];
    g[i][2] = kvd[(unsigned)aa.z + j];
    g[i][3] = kvd[(unsigned)aa.w + j];
  }

  h2 sam[10];
  float lg[10];
#pragma unroll
  for (int i = 0; i < 10; ++i) {
    const int s = i % 5;   // constant after unroll
    const uint4 wt = wwp[s];
    const unsigned g0 = g[s][0], g1 = g[s][1], g2 = g[s][2], g3 = g[s][3];
    if (i < 5) {           // refill slot s with pair i+5
      const int4 aa = *(const int4*)&pbuf[wv][2 * (i + 5) + half][0];
      wwp[s] = *(const uint4*)&pbuf[wv][2 * (i + 5) + half][4];
      g[s][0] = kvd[(unsigned)aa.x + j];
      g[s][1] = kvd[(unsigned)aa.y + j];
      g[s][2] = kvd[(unsigned)aa.z + j];
      g[s][3] = kvd[(unsigned)aa.w + j];
    }
    // packed bilinear: 4x v_pk_fma_f16
    h2 v = u2h(wt.x) * u2h(g0);
    v = u2h(wt.y) * u2h(g1) + v;
    v = u2h(wt.z) * u2h(g2) + v;
    v = u2h(wt.w) * u2h(g3) + v;
    sam[i] = v;
    // logit partial: v_dot2_f32_f16 (f32 accumulate)
    float part = (j < 16) ? __builtin_amdgcn_fdot2(qpk, v, qpe[i], false) : 0.f;
    part = dppadd<0xB1>(part);    // quad_perm xor1
    part = dppadd<0x4E>(part);    // quad_perm xor2
    part = dppadd<0x124>(part);   // row_ror:4
    part = dppadd<0x128>(part);   // row_ror:8 -> row16 sum
    lg[i] = part + __shfl_xor(part, 16, 64);
  }

  float mx = lg[0];
#pragma unroll
  for (int i = 1; i < 10; ++i) mx = fmaxf(mx, lg[i]);
  mx = fmaxf(mx, __shfl_xor(mx, 32, 64));
  float se = 0.f;
#pragma unroll
  for (int i = 0; i < 10; ++i) {
    lg[i] = __expf(lg[i] - mx);
    se += lg[i];
  }
  se += __shfl_xor(se, 32, 64);
  const float inv = 1.f / se;

  float ax = 0.f, ay = 0.f;
#pragma unroll
  for (int i = 0; i < 10; ++i) {
    ax = fmaf(lg[i], (float)sam[i][0], ax);
    ay = fmaf(lg[i], (float)sam[i][1], ay);
  }
  ax += __shfl_xor(ax, 32, 64);
  ay += __shfl_xor(ay, 32, 64);

  if (half == 0 && j >= 16) {
    const unsigned u = (unsigned)f2b(ax * inv) | ((unsigned)f2b(ay * inv) << 16);
    ((unsigned*)wtd)[(size_t)bn * 128 + h * 16 + (j - 16)] = u;
  }
}

// ---------------------------------------------------------------------------
extern "C" void kernel_launch(void* const* d_in, const int* in_sizes, int n_in,
                              void* d_out, int out_size, void* d_ws, size_t ws_size,
                              hipStream_t stream) {
  const float* in_feats = (const float*)d_in[0];
  const float* priors   = (const float*)d_in[1];
  const float* sfeats   = (const float*)d_in[2];
  const int*   shapes   = (const int*)d_in[3];
  const int*   starts   = (const int*)d_in[4];
  const float* W_off    = (const float*)d_in[5];
  const float* b_off    = (const float*)d_in[6];
  const float* W_q      = (const float*)d_in[7];
  const float* b_q      = (const float*)d_in[8];
  const float* W_kv     = (const float*)d_in[9];
  const float* b_kv     = (const float*)d_in[10];
  const float* pencs    = (const float*)d_in[11];
  const float* W_out    = (const float*)d_in[12];
  const float* b_out    = (const float*)d_in[13];
  float* out = (float*)d_out;

  char* w = (char*)d_ws;
  unsigned short* kvt = (unsigned short*)w;            // 44.7 MB (f16)
  w += (size_t)B_ * HH * S_ * 64 * 2;
  unsigned short* if_hi = (unsigned short*)w; w += (size_t)4096 * 256 * 2;
  unsigned short* if_lo = (unsigned short*)w; w += (size_t)4096 * 256 * 2;
  unsigned short* wkv_bf = (unsigned short*)w;  w += (size_t)512 * 256 * 2;
  unsigned short* wq_bf  = (unsigned short*)w;  w += (size_t)256 * 256 * 2;
  unsigned short* wout_bf = (unsigned short*)w; w += (size_t)256 * 256 * 2;
  unsigned short* woff_hi = (unsigned short*)w; w += (size_t)384 * 256 * 2;
  unsigned short* woff_lo = (unsigned short*)w; w += (size_t)384 * 256 * 2;
  float* offb = (float*)w;  w += (size_t)4096 * 384 * 4;
  float* qb   = (float*)w;  w += (size_t)4096 * 256 * 4;
  unsigned short* wtd_bf = (unsigned short*)w; w += (size_t)4096 * 256 * 2;

  // 1) small conversions only (736 blocks)
  cvt_all<<<F5 / 256, 256, 0, stream>>>(
      in_feats, W_kv, W_q, W_out, W_off,
      if_hi, if_lo, wkv_bf, wq_bf, wout_bf, woff_hi, woff_lo);

  // 2) off + q + kv (kv: f32-A staging + reg-cvt, fixed B swizzle, setprio)
  ubergemm<<<1536, 256, 0, stream>>>(
      sfeats, wkv_bf, if_hi, if_lo, woff_hi, woff_lo, wq_bf,
      b_kv, b_off, b_q, kvt, offb, qb);

  // 3) fused prep + sampling + attention (packed-f16 math)
  sample_attn6<<<(B_ * N_ * HH) / 4, 256, 0, stream>>>(
      kvt, offb, qb, priors, shapes, starts, pencs, wtd_bf);

  // 4) out = weighted @ W_out^T + b_out
  gemm_out<<<dim3(2, 32), 256, 0, stream>>>(wtd_bf, wout_bf, b_out, out);
}